// Round 1
// baseline (656.076 us; speedup 1.0000x reference)
//
#include <hip/hip_runtime.h>
#include <hip/hip_bf16.h>

#define BATCH 128
#define NPTS  2048
#define NDIM  3
#define NPROJ 100
#define NTHREADS 256

// One block per (b, l) pair: project P[b] and Q[b] onto direction proj[b,:,l],
// bitonic-sort both projected arrays in LDS, sum squared differences of the
// sorted arrays, write one partial sum per block to d_ws (deterministic).
__global__ __launch_bounds__(NTHREADS) void swd_pair_kernel(
    const float* __restrict__ P,
    const float* __restrict__ Q,
    const float* __restrict__ proj,
    float* __restrict__ partial) {
  const int blk = blockIdx.x;       // b * NPROJ + l
  const int b   = blk / NPROJ;
  const int l   = blk - b * NPROJ;
  const int tid = threadIdx.x;

  __shared__ float sp[NPTS];
  __shared__ float sq[NPTS];

  // Direction vector (D=3), broadcast via scalar loads.
  const float d0 = proj[(size_t)b * NDIM * NPROJ + 0 * NPROJ + l];
  const float d1 = proj[(size_t)b * NDIM * NPROJ + 1 * NPROJ + l];
  const float d2 = proj[(size_t)b * NDIM * NPROJ + 2 * NPROJ + l];

  const float* __restrict__ Pb = P + (size_t)b * NPTS * NDIM;
  const float* __restrict__ Qb = Q + (size_t)b * NPTS * NDIM;

  // Project: each thread handles 8 points.
  for (int n = tid; n < NPTS; n += NTHREADS) {
    const float p0 = Pb[n * 3 + 0], p1 = Pb[n * 3 + 1], p2 = Pb[n * 3 + 2];
    const float q0 = Qb[n * 3 + 0], q1 = Qb[n * 3 + 1], q2 = Qb[n * 3 + 2];
    sp[n] = p0 * d0 + p1 * d1 + p2 * d2;
    sq[n] = q0 * d0 + q1 * d1 + q2 * d2;
  }
  __syncthreads();

  // Bitonic sort both arrays (ascending), sharing barriers.
  for (int k = 2; k <= NPTS; k <<= 1) {
    for (int j = k >> 1; j > 0; j >>= 1) {
      for (int t = tid; t < NPTS / 2; t += NTHREADS) {
        const int i = ((t & ~(j - 1)) << 1) | (t & (j - 1));
        const int partner = i | j;
        const bool up = ((i & k) == 0);
        {
          const float a = sp[i], c = sp[partner];
          if ((a > c) == up) { sp[i] = c; sp[partner] = a; }
        }
        {
          const float a = sq[i], c = sq[partner];
          if ((a > c) == up) { sq[i] = c; sq[partner] = a; }
        }
      }
      __syncthreads();
    }
  }

  // Sum of squared differences of sorted arrays.
  float acc = 0.f;
  for (int n = tid; n < NPTS; n += NTHREADS) {
    const float d = sp[n] - sq[n];
    acc += d * d;
  }
  // Wave reduce (width 64) then cross-wave via LDS.
  for (int off = 32; off > 0; off >>= 1) acc += __shfl_down(acc, off, 64);
  __shared__ float wsum[NTHREADS / 64];
  if ((tid & 63) == 0) wsum[tid >> 6] = acc;
  __syncthreads();
  if (tid == 0) partial[blk] = wsum[0] + wsum[1] + wsum[2] + wsum[3];
}

// Single block: per-batch reduce over L partials, sqrt, mean over B.
__global__ __launch_bounds__(BATCH) void swd_finalize_kernel(
    const float* __restrict__ partial, float* __restrict__ out) {
  const int b = threadIdx.x;  // 0..127
  float s = 0.f;
  for (int l = 0; l < NPROJ; ++l) s += partial[b * NPROJ + l];
  float swd = sqrtf(s / (float)(NPTS * NPROJ));
  for (int off = 32; off > 0; off >>= 1) swd += __shfl_down(swd, off, 64);
  __shared__ float wsum[BATCH / 64];
  if ((threadIdx.x & 63) == 0) wsum[threadIdx.x >> 6] = swd;
  __syncthreads();
  if (threadIdx.x == 0) out[0] = (wsum[0] + wsum[1]) / (float)BATCH;
}

extern "C" void kernel_launch(void* const* d_in, const int* in_sizes, int n_in,
                              void* d_out, int out_size, void* d_ws, size_t ws_size,
                              hipStream_t stream) {
  const float* P    = (const float*)d_in[0];
  const float* Q    = (const float*)d_in[1];
  const float* proj = (const float*)d_in[2];
  float* out = (float*)d_out;
  float* partial = (float*)d_ws;  // BATCH*NPROJ floats = 51.2 KB

  swd_pair_kernel<<<BATCH * NPROJ, NTHREADS, 0, stream>>>(P, Q, proj, partial);
  swd_finalize_kernel<<<1, BATCH, 0, stream>>>(partial, out);
}

// Round 2
// 289.278 us; speedup vs baseline: 2.2680x; 2.2680x over previous
//
#include <hip/hip_runtime.h>
#include <hip/hip_bf16.h>

#define BATCH 128
#define NPTS  2048
#define NDIM  3
#define NPROJ 100
#define NTH   128   // 2 waves per block
#define EPT   16    // elements per thread; 128*16 = 2048

// ---------------------------------------------------------------------------
// Cross-lane xor-exchange: returns {r0, r1} = {v[lane], v[lane^D]} in
// UNSPECIFIED order (both values present per lane). Consumers use min/max so
// the order never matters.
// ---------------------------------------------------------------------------
template<int D>
__device__ __forceinline__ void xor_pair(float v, float& r0, float& r1) {
  if constexpr (D == 1) {
    r0 = v;
    r1 = __int_as_float(__builtin_amdgcn_mov_dpp(__float_as_int(v), 0xB1, 0xF, 0xF, true)); // quad_perm [1,0,3,2]
  } else if constexpr (D == 2) {
    r0 = v;
    r1 = __int_as_float(__builtin_amdgcn_mov_dpp(__float_as_int(v), 0x4E, 0xF, 0xF, true)); // quad_perm [2,3,0,1]
  } else if constexpr (D == 4) {
    r0 = v;
    r1 = __int_as_float(__builtin_amdgcn_ds_swizzle(__float_as_int(v), 0x101F)); // xor 4
  } else if constexpr (D == 8) {
    r0 = v;
    r1 = __int_as_float(__builtin_amdgcn_ds_swizzle(__float_as_int(v), 0x201F)); // xor 8
  } else if constexpr (D == 16) {
#if __has_builtin(__builtin_amdgcn_permlane16_swap)
    auto r = __builtin_amdgcn_permlane16_swap(__float_as_int(v), __float_as_int(v), false, false);
    r0 = __int_as_float(r[0]);
    r1 = __int_as_float(r[1]);
#else
    r0 = v;
    r1 = __int_as_float(__builtin_amdgcn_ds_swizzle(__float_as_int(v), 0x401F)); // xor 16
#endif
  } else { // D == 32
#if __has_builtin(__builtin_amdgcn_permlane32_swap)
    auto r = __builtin_amdgcn_permlane32_swap(__float_as_int(v), __float_as_int(v), false, false);
    r0 = __int_as_float(r[0]);
    r1 = __int_as_float(r[1]);
#else
    r0 = v;
    r1 = __shfl_xor(v, 32, 64);
#endif
  }
}

// ---------------------------------------------------------------------------
// One bitonic substep (stage K, stride J) on both register arrays.
// Element index: i = tid*EPT + s  (s = bits 0-3, tid = bits 4-10).
// ---------------------------------------------------------------------------
template<int K, int J>
__device__ __forceinline__ void substep(float vp[EPT], float vq[EPT],
                                        const int tid, float* sbuf) {
  if constexpr (J >= 16 && J <= 512) {
    // cross-lane within a wave: partner thread = tid ^ (J>>4)
    constexpr int D = J >> 4;
    const bool keepmin = (((tid & (K >> 4)) == 0) == ((tid & D) == 0));
#pragma unroll
    for (int s = 0; s < EPT; ++s) {
      float a, o;
      xor_pair<D>(vp[s], a, o);
      vp[s] = keepmin ? fminf(a, o) : fmaxf(a, o);
    }
#pragma unroll
    for (int s = 0; s < EPT; ++s) {
      float a, o;
      xor_pair<D>(vq[s], a, o);
      vq[s] = keepmin ? fminf(a, o) : fmaxf(a, o);
    }
  } else if constexpr (J == 1024) {
    // cross-wave exchange via LDS (only K==2048, direction 'up' everywhere)
    static_assert(K == NPTS, "J=1024 only in final stage");
    float* sp = sbuf;
    float* sq = sbuf + NPTS;
#pragma unroll
    for (int s = 0; s < EPT; s += 4) {
      *reinterpret_cast<float4*>(sp + tid * EPT + s) =
          make_float4(vp[s], vp[s + 1], vp[s + 2], vp[s + 3]);
      *reinterpret_cast<float4*>(sq + tid * EPT + s) =
          make_float4(vq[s], vq[s + 1], vq[s + 2], vq[s + 3]);
    }
    __syncthreads();
    const int po = (tid ^ 64) * EPT;
    const bool keepmin = ((tid & 64) == 0);
#pragma unroll
    for (int s = 0; s < EPT; s += 4) {
      const float4 op4 = *reinterpret_cast<const float4*>(sp + po + s);
      const float4 oq4 = *reinterpret_cast<const float4*>(sq + po + s);
      vp[s + 0] = keepmin ? fminf(vp[s + 0], op4.x) : fmaxf(vp[s + 0], op4.x);
      vp[s + 1] = keepmin ? fminf(vp[s + 1], op4.y) : fmaxf(vp[s + 1], op4.y);
      vp[s + 2] = keepmin ? fminf(vp[s + 2], op4.z) : fmaxf(vp[s + 2], op4.z);
      vp[s + 3] = keepmin ? fminf(vp[s + 3], op4.w) : fmaxf(vp[s + 3], op4.w);
      vq[s + 0] = keepmin ? fminf(vq[s + 0], oq4.x) : fmaxf(vq[s + 0], oq4.x);
      vq[s + 1] = keepmin ? fminf(vq[s + 1], oq4.y) : fmaxf(vq[s + 1], oq4.y);
      vq[s + 2] = keepmin ? fminf(vq[s + 2], oq4.z) : fmaxf(vq[s + 2], oq4.z);
      vq[s + 3] = keepmin ? fminf(vq[s + 3], oq4.w) : fmaxf(vq[s + 3], oq4.w);
    }
  } else {
    // J <= 8: in-register slot compare-exchange
#pragma unroll
    for (int s = 0; s < EPT; ++s) {
      if ((s & J) == 0) {
        const int p = s | J;
        const bool up = (K <= 8) ? ((s & K) == 0) : ((tid & (K >> 4)) == 0);
        {
          const float a = vp[s], b = vp[p];
          const float lo = fminf(a, b), hi = fmaxf(a, b);
          vp[s] = up ? lo : hi;
          vp[p] = up ? hi : lo;
        }
        {
          const float a = vq[s], b = vq[p];
          const float lo = fminf(a, b), hi = fmaxf(a, b);
          vq[s] = up ? lo : hi;
          vq[p] = up ? hi : lo;
        }
      }
    }
  }
}

template<int K, int J>
__device__ __forceinline__ void sort_from(float vp[EPT], float vq[EPT],
                                          const int tid, float* sbuf) {
  substep<K, J>(vp, vq, tid, sbuf);
  if constexpr (J > 1) {
    sort_from<K, (J >> 1)>(vp, vq, tid, sbuf);
  } else if constexpr (K < NPTS) {
    sort_from<(K << 1), K>(vp, vq, tid, sbuf);
  }
}

// ---------------------------------------------------------------------------
// One block per (b, l) pair. Project, register-bitonic-sort both arrays,
// write one partial SSD per block (deterministic).
// ---------------------------------------------------------------------------
__global__ __launch_bounds__(NTH) void swd_sort_kernel(
    const float* __restrict__ P, const float* __restrict__ Q,
    const float* __restrict__ proj, float* __restrict__ partial) {
  __shared__ float sbuf[2 * NPTS];  // 16 KB, used once (j=1024) + final reduce
  const int blk = blockIdx.x;  // b * NPROJ + l
  const int b = blk / NPROJ;
  const int l = blk - b * NPROJ;
  const int tid = threadIdx.x;

  const float d0 = proj[b * NDIM * NPROJ + l];
  const float d1 = proj[b * NDIM * NPROJ + NPROJ + l];
  const float d2 = proj[b * NDIM * NPROJ + 2 * NPROJ + l];

  float vp[EPT], vq[EPT];
  const float4* Pb = reinterpret_cast<const float4*>(P + (size_t)b * NPTS * NDIM) + tid * 12;
  const float4* Qb = reinterpret_cast<const float4*>(Q + (size_t)b * NPTS * NDIM) + tid * 12;
#pragma unroll
  for (int c = 0; c < 4; ++c) {  // 3 float4 = 4 points = 4 slots
    const float4 x = Pb[c * 3 + 0], y = Pb[c * 3 + 1], z = Pb[c * 3 + 2];
    vp[c * 4 + 0] = x.x * d0 + x.y * d1 + x.z * d2;
    vp[c * 4 + 1] = x.w * d0 + y.x * d1 + y.y * d2;
    vp[c * 4 + 2] = y.z * d0 + y.w * d1 + z.x * d2;
    vp[c * 4 + 3] = z.y * d0 + z.z * d1 + z.w * d2;
  }
#pragma unroll
  for (int c = 0; c < 4; ++c) {
    const float4 x = Qb[c * 3 + 0], y = Qb[c * 3 + 1], z = Qb[c * 3 + 2];
    vq[c * 4 + 0] = x.x * d0 + x.y * d1 + x.z * d2;
    vq[c * 4 + 1] = x.w * d0 + y.x * d1 + y.y * d2;
    vq[c * 4 + 2] = y.z * d0 + y.w * d1 + z.x * d2;
    vq[c * 4 + 3] = z.y * d0 + z.z * d1 + z.w * d2;
  }

  sort_from<2, 1>(vp, vq, tid, sbuf);

  float acc = 0.f;
#pragma unroll
  for (int s = 0; s < EPT; ++s) {
    const float d = vp[s] - vq[s];
    acc += d * d;
  }
#pragma unroll
  for (int off = 32; off > 0; off >>= 1) acc += __shfl_down(acc, off, 64);
  __syncthreads();  // sbuf reads from j=1024 step must drain before reuse
  if ((tid & 63) == 0) sbuf[tid >> 6] = acc;
  __syncthreads();
  if (tid == 0) partial[blk] = sbuf[0] + sbuf[1];
}

// Single block: per-batch reduce over L partials, sqrt, mean over B.
__global__ __launch_bounds__(BATCH) void swd_finalize_kernel(
    const float* __restrict__ partial, float* __restrict__ out) {
  const int b = threadIdx.x;  // 0..127
  float s = 0.f;
  for (int l = 0; l < NPROJ; ++l) s += partial[b * NPROJ + l];
  float swd = sqrtf(s / (float)(NPTS * NPROJ));
  for (int off = 32; off > 0; off >>= 1) swd += __shfl_down(swd, off, 64);
  __shared__ float wsum[BATCH / 64];
  if ((threadIdx.x & 63) == 0) wsum[threadIdx.x >> 6] = swd;
  __syncthreads();
  if (threadIdx.x == 0) out[0] = (wsum[0] + wsum[1]) / (float)BATCH;
}

extern "C" void kernel_launch(void* const* d_in, const int* in_sizes, int n_in,
                              void* d_out, int out_size, void* d_ws, size_t ws_size,
                              hipStream_t stream) {
  const float* P    = (const float*)d_in[0];
  const float* Q    = (const float*)d_in[1];
  const float* proj = (const float*)d_in[2];
  float* out = (float*)d_out;
  float* partial = (float*)d_ws;  // BATCH*NPROJ floats = 51.2 KB

  swd_sort_kernel<<<BATCH * NPROJ, NTH, 0, stream>>>(P, Q, proj, partial);
  swd_finalize_kernel<<<1, BATCH, 0, stream>>>(partial, out);
}

// Round 3
// 246.017 us; speedup vs baseline: 2.6668x; 1.1758x over previous
//
#include <hip/hip_runtime.h>
#include <hip/hip_bf16.h>

#define BATCH 128
#define NPTS  2048
#define NDIM  3
#define NPROJ 100
#define NTH   128   // 2 waves per block
#define EPT   16    // elements per thread; 128*16 = 2048

// ---------------------------------------------------------------------------
// Exact cross-lane xor shuffle: returns v[lane ^ M].
// Masks 1,2,3 -> DPP quad_perm (VALU pipe).
// Masks 4,7,8,15,16,31 -> ds_swizzle bit-mode (LDS pipe, 32-lane groups ok).
// Masks 32,63 -> ds_bpermute with precomputed byte address (LDS pipe, wave64).
// ---------------------------------------------------------------------------
template<int M>
__device__ __forceinline__ float shx(float v, int a32, int a63) {
  const int x = __float_as_int(v);
  int r;
  if constexpr (M == 1)       r = __builtin_amdgcn_mov_dpp(x, 0xB1, 0xF, 0xF, true); // [1,0,3,2]
  else if constexpr (M == 2)  r = __builtin_amdgcn_mov_dpp(x, 0x4E, 0xF, 0xF, true); // [2,3,0,1]
  else if constexpr (M == 3)  r = __builtin_amdgcn_mov_dpp(x, 0x1B, 0xF, 0xF, true); // [3,2,1,0]
  else if constexpr (M == 4)  r = __builtin_amdgcn_ds_swizzle(x, 0x101F);
  else if constexpr (M == 7)  r = __builtin_amdgcn_ds_swizzle(x, 0x1C1F);
  else if constexpr (M == 8)  r = __builtin_amdgcn_ds_swizzle(x, 0x201F);
  else if constexpr (M == 15) r = __builtin_amdgcn_ds_swizzle(x, 0x3C1F);
  else if constexpr (M == 16) r = __builtin_amdgcn_ds_swizzle(x, 0x401F);
  else if constexpr (M == 31) r = __builtin_amdgcn_ds_swizzle(x, 0x7C1F);
  else if constexpr (M == 32) r = __builtin_amdgcn_ds_bpermute(a32, x);
  else                        r = __builtin_amdgcn_ds_bpermute(a63, x);
  return __int_as_float(r);
}

// Intra-thread reversal CE: within each group of G slots, pair (r, G-1-r).
// Min always to the lower slot (fixed direction).
template<int G>
__device__ __forceinline__ void intra_rev(float v[EPT]) {
#pragma unroll
  for (int g = 0; g < EPT; g += G) {
#pragma unroll
    for (int r = 0; r < G / 2; ++r) {
      const float a = v[g + r], b = v[g + G - 1 - r];
      v[g + r] = fminf(a, b);
      v[g + G - 1 - r] = fmaxf(a, b);
    }
  }
}

// Intra-thread xor CE: pair (s, s|J), min to lower slot.
template<int J>
__device__ __forceinline__ void intra_xor(float v[EPT]) {
#pragma unroll
  for (int s = 0; s < EPT; ++s) {
    if ((s & J) == 0) {
      const float a = v[s], b = v[s | J];
      v[s] = fminf(a, b);
      v[s | J] = fmaxf(a, b);
    }
  }
}

// Cross-lane reversal CE (stage K, W=K/16 threads per block): partner thread
// tid^M (M=W-1), partner slot 15-s. Upper half (tid&HB, HB=W/2) takes max.
template<int M, int HB>
__device__ __forceinline__ void cross_rev(float v[EPT], const int tid,
                                          const int a32, const int a63) {
  float o[EPT];
#pragma unroll
  for (int s = 0; s < EPT; ++s) o[s] = shx<M>(v[15 - s], a32, a63);
  if (tid & HB) {
#pragma unroll
    for (int s = 0; s < EPT; ++s) v[s] = fmaxf(v[s], o[s]);
  } else {
#pragma unroll
    for (int s = 0; s < EPT; ++s) v[s] = fminf(v[s], o[s]);
  }
}

// Cross-lane xor CE at thread-stride D: min to lower thread (fixed dir).
template<int D>
__device__ __forceinline__ void cross_xor(float v[EPT], const int tid,
                                          const int a32, const int a63) {
  float o[EPT];
#pragma unroll
  for (int s = 0; s < EPT; ++s) o[s] = shx<D>(v[s], a32, a63);
  if (tid & D) {
#pragma unroll
    for (int s = 0; s < EPT; ++s) v[s] = fmaxf(v[s], o[s]);
  } else {
#pragma unroll
    for (int s = 0; s < EPT; ++s) v[s] = fminf(v[s], o[s]);
  }
}

// Final-stage reversal across the two waves (i <-> 2047-i) via LDS.
// Wave 0 takes min, wave 1 takes max (wave-uniform, no selects).
__device__ __forceinline__ void lds_rev(float vp[EPT], float vq[EPT],
                                        const int tid, float* sbuf) {
  float4* s4 = reinterpret_cast<float4*>(sbuf);  // 512 float4 P, 512 float4 Q
#pragma unroll
  for (int c = 0; c < 4; ++c) {
    s4[tid * 4 + c] = make_float4(vp[4 * c], vp[4 * c + 1], vp[4 * c + 2], vp[4 * c + 3]);
    s4[512 + tid * 4 + c] = make_float4(vq[4 * c], vq[4 * c + 1], vq[4 * c + 2], vq[4 * c + 3]);
  }
  __syncthreads();
  const int pb = (tid ^ 127) * 4;
  float op[EPT], oq[EPT];
#pragma unroll
  for (int c = 0; c < 4; ++c) {
    const float4 w = s4[pb + 3 - c];
    op[4 * c + 0] = w.w; op[4 * c + 1] = w.z; op[4 * c + 2] = w.y; op[4 * c + 3] = w.x;
    const float4 u = s4[512 + pb + 3 - c];
    oq[4 * c + 0] = u.w; oq[4 * c + 1] = u.z; oq[4 * c + 2] = u.y; oq[4 * c + 3] = u.x;
  }
  if (tid & 64) {
#pragma unroll
    for (int s = 0; s < EPT; ++s) { vp[s] = fmaxf(vp[s], op[s]); vq[s] = fmaxf(vq[s], oq[s]); }
  } else {
#pragma unroll
    for (int s = 0; s < EPT; ++s) { vp[s] = fminf(vp[s], op[s]); vq[s] = fminf(vq[s], oq[s]); }
  }
}

#define IR(G)     intra_rev<G>(vp); intra_rev<G>(vq)
#define IX(J)     intra_xor<J>(vp); intra_xor<J>(vq)
#define CRV(M,HB) cross_rev<M,HB>(vp, tid, a32, a63); cross_rev<M,HB>(vq, tid, a32, a63)
#define CXR(D)    cross_xor<D>(vp, tid, a32, a63); cross_xor<D>(vq, tid, a32, a63)

// ---------------------------------------------------------------------------
// One block per (b, l) pair. Project, fixed-direction register bitonic sort,
// write one partial SSD per block (deterministic).
// ---------------------------------------------------------------------------
__global__ __launch_bounds__(NTH) void swd_sort_kernel(
    const float* __restrict__ P, const float* __restrict__ Q,
    const float* __restrict__ proj, float* __restrict__ partial) {
  __shared__ float sbuf[2 * NPTS];  // 16 KB; final reversal + reduce
  const int blk = blockIdx.x;  // b * NPROJ + l
  const int b = blk / NPROJ;
  const int l = blk - b * NPROJ;
  const int tid = threadIdx.x;
  const int lane = tid & 63;
  const int a32 = ((lane ^ 32) << 2);
  const int a63 = ((lane ^ 63) << 2);

  const float d0 = proj[b * NDIM * NPROJ + l];
  const float d1 = proj[b * NDIM * NPROJ + NPROJ + l];
  const float d2 = proj[b * NDIM * NPROJ + 2 * NPROJ + l];

  float vp[EPT], vq[EPT];
  const float4* Pb = reinterpret_cast<const float4*>(P + (size_t)b * NPTS * NDIM) + tid * 12;
  const float4* Qb = reinterpret_cast<const float4*>(Q + (size_t)b * NPTS * NDIM) + tid * 12;
#pragma unroll
  for (int c = 0; c < 4; ++c) {  // 3 float4 = 4 points = 4 slots
    const float4 x = Pb[c * 3 + 0], y = Pb[c * 3 + 1], z = Pb[c * 3 + 2];
    vp[c * 4 + 0] = x.x * d0 + x.y * d1 + x.z * d2;
    vp[c * 4 + 1] = x.w * d0 + y.x * d1 + y.y * d2;
    vp[c * 4 + 2] = y.z * d0 + y.w * d1 + z.x * d2;
    vp[c * 4 + 3] = z.y * d0 + z.z * d1 + z.w * d2;
  }
#pragma unroll
  for (int c = 0; c < 4; ++c) {
    const float4 x = Qb[c * 3 + 0], y = Qb[c * 3 + 1], z = Qb[c * 3 + 2];
    vq[c * 4 + 0] = x.x * d0 + x.y * d1 + x.z * d2;
    vq[c * 4 + 1] = x.w * d0 + y.x * d1 + y.y * d2;
    vq[c * 4 + 2] = y.z * d0 + y.w * d1 + z.x * d2;
    vq[c * 4 + 3] = z.y * d0 + z.z * d1 + z.w * d2;
  }

  // ---- fixed-direction bitonic sort of 2048 (layout i = tid*16 + s) ----
  // local: runs of 16 (ascending everywhere)
  IR(2);
  IR(4); IX(1);
  IR(8); IX(2); IX(1);
  IR(16); IX(4); IX(2); IX(1);
  // K=32
  CRV(1, 1); IX(8); IX(4); IX(2); IX(1);
  // K=64
  CRV(3, 2); CXR(1); IX(8); IX(4); IX(2); IX(1);
  // K=128
  CRV(7, 4); CXR(2); CXR(1); IX(8); IX(4); IX(2); IX(1);
  // K=256
  CRV(15, 8); CXR(4); CXR(2); CXR(1); IX(8); IX(4); IX(2); IX(1);
  // K=512
  CRV(31, 16); CXR(8); CXR(4); CXR(2); CXR(1); IX(8); IX(4); IX(2); IX(1);
  // K=1024
  CRV(63, 32); CXR(16); CXR(8); CXR(4); CXR(2); CXR(1); IX(8); IX(4); IX(2); IX(1);
  // K=2048 (reversal crosses waves -> LDS)
  lds_rev(vp, vq, tid, sbuf);
  CXR(32); CXR(16); CXR(8); CXR(4); CXR(2); CXR(1); IX(8); IX(4); IX(2); IX(1);

  // ---- SSD of sorted arrays ----
  float acc = 0.f;
#pragma unroll
  for (int s = 0; s < EPT; ++s) {
    const float d = vp[s] - vq[s];
    acc += d * d;
  }
#pragma unroll
  for (int off = 32; off > 0; off >>= 1) acc += __shfl_down(acc, off, 64);
  __syncthreads();  // lds_rev reads must drain before sbuf reuse
  if ((tid & 63) == 0) sbuf[tid >> 6] = acc;
  __syncthreads();
  if (tid == 0) partial[blk] = sbuf[0] + sbuf[1];
}

// Single block: per-batch reduce over L partials, sqrt, mean over B.
__global__ __launch_bounds__(BATCH) void swd_finalize_kernel(
    const float* __restrict__ partial, float* __restrict__ out) {
  const int b = threadIdx.x;  // 0..127
  float s = 0.f;
  for (int l = 0; l < NPROJ; ++l) s += partial[b * NPROJ + l];
  float swd = sqrtf(s / (float)(NPTS * NPROJ));
  for (int off = 32; off > 0; off >>= 1) swd += __shfl_down(swd, off, 64);
  __shared__ float wsum[BATCH / 64];
  if ((threadIdx.x & 63) == 0) wsum[threadIdx.x >> 6] = swd;
  __syncthreads();
  if (threadIdx.x == 0) out[0] = (wsum[0] + wsum[1]) / (float)BATCH;
}

extern "C" void kernel_launch(void* const* d_in, const int* in_sizes, int n_in,
                              void* d_out, int out_size, void* d_ws, size_t ws_size,
                              hipStream_t stream) {
  const float* P    = (const float*)d_in[0];
  const float* Q    = (const float*)d_in[1];
  const float* proj = (const float*)d_in[2];
  float* out = (float*)d_out;
  float* partial = (float*)d_ws;  // BATCH*NPROJ floats = 51.2 KB

  swd_sort_kernel<<<BATCH * NPROJ, NTH, 0, stream>>>(P, Q, proj, partial);
  swd_finalize_kernel<<<1, BATCH, 0, stream>>>(partial, out);
}